// Round 17
// baseline (37.306 us; speedup 1.0000x reference)
//
#include <hip/hip_runtime.h>
#include <hip/hip_fp16.h>
#include <math.h>

#define BB 16
#define CC 3
#define HH 512
#define WW 512
#define HW (HH * WW)
#define RAD 5
#define SEGV 32
#define NSEG (HH / SEGV)            // 16 segments per image
#define NSTRIP 5                    // 5 overlapping 128-col strips, 116 valid each
#define STRIPW 116
#define NTASK (BB * NSEG * NSTRIP)  // 1280 wave-tasks = 1280 single-wave blocks
#define NBLK NTASK                  // 5 blocks/CU exactly (even distribution)
#define NITER (SEGV + 2 * RAD)      // 42 row iterations (halo amp 1.31x)

// ---- DPP wave-shift helpers (VALU pipe, no DS) ----
#define DPP_WAVE_SHL1 0x130
#define DPP_WAVE_SHR1 0x138

template <int CTRL>
__device__ __forceinline__ float dpp_f(float x) {
    union { float f; int i; } u, o;
    u.f = x;
    o.i = __builtin_amdgcn_update_dpp(0, u.i, CTRL, 0xF, 0xF, true);
    return o.f;
}
template <int CTRL>
__device__ __forceinline__ __half2 dpp_h2(__half2 x) {
    union { __half2 h; int i; } u, o;
    u.h = x;
    o.i = __builtin_amdgcn_update_dpp(0, u.i, CTRL, 0xF, 0xF, true);
    return o.h;
}
#define SHL1F(x) dpp_f<DPP_WAVE_SHL1>(x)
#define SHR1F(x) dpp_f<DPP_WAVE_SHR1>(x)
#define SHL1H(x) dpp_h2<DPP_WAVE_SHL1>(x)
#define SHR1H(x) dpp_h2<DPP_WAVE_SHR1>(x)

// R14 champion body, SEGV 16 -> 32 (-19% total iters, -21% bytes),
// single-wave blocks (no LDS, no barriers anywhere).
__global__ __launch_bounds__(64) void fused_dpp(
    const float* __restrict__ pred, const float* __restrict__ target,
    float* __restrict__ ws_sq, float* __restrict__ ws_cos)
{
    const int lane = threadIdx.x;

    // bijective XCD-contiguous swizzle (1280 % 8 == 0): 160 blocks/XCD = 2 images
    const int bid = (int)blockIdx.x;
    const int swz = (bid & 7) * (NBLK / 8) + (bid >> 3);

    const int img   = swz / (NSEG * NSTRIP);
    const int rem   = swz % (NSEG * NSTRIP);
    const int seg   = rem / NSTRIP;
    const int strip = rem - seg * NSTRIP;

    const int y0   = seg * SEGV;
    const int col0 = strip * STRIPW - 6 + lane * 2;      // even
    const int colc = min(max(col0, 0), WW - 2);
    const float mx = (col0 >= 0 && col0 < WW) ? 1.f : 0.f;
    const bool vout = (lane >= 3) && (lane <= 60) && (col0 < WW);

    const long base = (long)img * (CC * HW);

    // prefetch row 0 (issue-early), depth-1 (VGPR-lean)
    float2 P0, P1, P2, T0, T1, T2;
    {
        const int y  = y0 - RAD;
        const int yc = y < 0 ? 0 : y;
        const long off = base + (long)yc * WW + colc;
        P0 = *(const float2*)(pred + off);
        P1 = *(const float2*)(pred + off + HW);
        P2 = *(const float2*)(pred + off + 2 * HW);
        T0 = *(const float2*)(target + off);
        T1 = *(const float2*)(target + off + HW);
        T2 = *(const float2*)(target + off + 2 * HW);
    }

    __half2 ring0[11], ring1[11], ringT[11];   // (hd0,hp0), (hd1,hp1), (ht0,ht1)
    float Sd0=0.f, Sd1=0.f, Sp0=0.f, Sp1=0.f, St0=0.f, St1=0.f;
    float sq = 0.f, cosacc = 0.f;

    #pragma unroll
    for (int it = 0; it < NITER; ++it) {
        const int y = y0 - RAD + it;
        const float msk = (y >= 0 && y < HH) ? mx : 0.f;

        const float2 p0=P0, p1=P1, p2=P2, t0=T0, t1=T1, t2=T2;
        if (it + 1 < NITER) {                     // prefetch next row
            const int y2  = y0 - RAD + it + 1;
            const int yc2 = min(max(y2, 0), HH - 1);
            const long off2 = base + (long)yc2 * WW + colc;
            P0 = *(const float2*)(pred + off2);
            P1 = *(const float2*)(pred + off2 + HW);
            P2 = *(const float2*)(pred + off2 + 2 * HW);
            T0 = *(const float2*)(target + off2);
            T1 = *(const float2*)(target + off2 + HW);
            T2 = *(const float2*)(target + off2 + 2 * HW);
        }

        // per-pixel dot/pp/tt, masked (zero padding outside image)
        const float ad = (p0.x*t0.x + p1.x*t1.x + p2.x*t2.x) * msk;
        const float bd = (p0.y*t0.y + p1.y*t1.y + p2.y*t2.y) * msk;
        const float ap = (p0.x*p0.x + p1.x*p1.x + p2.x*p2.x) * msk;
        const float bp = (p0.y*p0.y + p1.y*p1.y + p2.y*p2.y) * msk;
        const float at = (t0.x*t0.x + t1.x*t1.x + t2.x*t2.x) * msk;
        const float bt = (t0.y*t0.y + t1.y*t1.y + t2.y*t2.y) * msk;

        // PSNR squared error from maps: sum_c (p-t)^2 = pp - 2*dot + tt
        if (it >= RAD && it < RAD + SEGV && vout) {
            sq += (ap + at - 2.f * ad) + (bp + bt - 2.f * bd);
        }

        // ---- horizontal 11-window via DPP wave shifts (VALU only) ----
        __half2 h0dp, h1dp;
        {
            const __half2 Pk = __floats2half2_rn(ad + bd, ap + bp);
            const __half2 Ak = __floats2half2_rn(ad, ap);
            const __half2 Bk = __floats2half2_rn(bd, bp);
            __half2 w = Pk;
            w = __hadd2(Pk, SHR1H(w));
            w = __hadd2(Pk, SHR1H(w));
            w = __hadd2(Pk, SHR1H(w));
            w = __hadd2(Pk, SHR1H(w));            // sum pr_{i..i+4}
            const __half2 S5 = SHL1H(SHL1H(w));   // sum pr_{i-2..i+2}
            const __half2 eB = SHL1H(SHL1H(SHL1H(Bk)));
            const __half2 eA = SHR1H(SHR1H(SHR1H(Ak)));
            h0dp = __hadd2(eB, S5);
            h1dp = __hadd2(S5, eA);
        }
        __half2 hT;
        {
            const float pr = at + bt;
            float w = pr;
            w = pr + SHR1F(w);
            w = pr + SHR1F(w);
            w = pr + SHR1F(w);
            w = pr + SHR1F(w);
            const float S5 = SHL1F(SHL1F(w));
            const float eB = SHL1F(SHL1F(SHL1F(bt)));
            const float eA = SHR1F(SHR1F(SHR1F(at)));
            hT = __floats2half2_rn(eB + S5, S5 + eA);
        }

        // accumulate the QUANTIZED values -> ring subtract cancels exactly
        const float2 f0 = __half22float2(h0dp);
        const float2 f1 = __half22float2(h1dp);
        const float2 fT = __half22float2(hT);
        Sd0 += f0.x; Sp0 += f0.y;
        Sd1 += f1.x; Sp1 += f1.y;
        St0 += fT.x; St1 += fT.y;

        if (it >= 10) {
            if (vout) {
                cosacc += Sd0 * rsqrtf(fmaxf(Sp0 * St0, 1e-20f));
                cosacc += Sd1 * rsqrtf(fmaxf(Sp1 * St1, 1e-20f));
            }
            const float2 o0 = __half22float2(ring0[(it + 1) % 11]);
            const float2 o1 = __half22float2(ring1[(it + 1) % 11]);
            const float2 oT = __half22float2(ringT[(it + 1) % 11]);
            Sd0 -= o0.x; Sp0 -= o0.y;
            Sd1 -= o1.x; Sp1 -= o1.y;
            St0 -= oT.x; St1 -= oT.y;
        }
        ring0[it % 11] = h0dp;
        ring1[it % 11] = h1dp;
        ringT[it % 11] = hT;
    }

    // wave reduce -> per-block (= per-wave) partial stores
    #pragma unroll
    for (int o = 32; o > 0; o >>= 1) {
        cosacc += __shfl_down(cosacc, o);
        sq     += __shfl_down(sq, o);
    }
    if (lane == 0) {
        ws_cos[swz] = cosacc;
        ws_sq [swz] = sq;
    }
}

// ---------------- finalize: 1280 sq + 1280 cos partials ----------------
__global__ __launch_bounds__(256) void finalize4(
    const float* __restrict__ ws_sq, const float* __restrict__ ws_cos,
    float* __restrict__ out)
{
    __shared__ float sq_b[16];
    __shared__ float cred[4];
    const int tid = threadIdx.x;

    // sq: 80 partials per image; 16 threads/image, 5 values each
    const int b = tid >> 4, j = tid & 15;
    float s = 0.f;
    #pragma unroll
    for (int k = 0; k < 5; ++k) s += ws_sq[b * 80 + j * 5 + k];
    #pragma unroll
    for (int o = 8; o > 0; o >>= 1) s += __shfl_down(s, o, 16);
    if (j == 0) sq_b[b] = s;

    float c = 0.f;
    #pragma unroll
    for (int k = 0; k < 5; ++k) c += ws_cos[tid + 256 * k];
    #pragma unroll
    for (int o = 32; o > 0; o >>= 1) c += __shfl_down(c, o);
    if ((tid & 63) == 0) cred[tid >> 6] = c;
    __syncthreads();

    if (tid == 0) {
        const float csum = cred[0] + cred[1] + cred[2] + cred[3];
        const float scale = 4.342944819032518f;   // 10 / ln(10)
        float lsum = 0.f;
        for (int bb = 0; bb < 16; ++bb)
            lsum += logf(sq_b[bb] / (float)(CC * HW) + 1e-8f);
        out[0] = scale * (lsum / (float)BB) + (1.f - csum / (float)(BB * HW));
    }
}

extern "C" void kernel_launch(void* const* d_in, const int* in_sizes, int n_in,
                              void* d_out, int out_size, void* d_ws, size_t ws_size,
                              hipStream_t stream)
{
    const float* pred   = (const float*)d_in[0];
    const float* target = (const float*)d_in[1];

    float* ws_sq  = (float*)d_ws;                        // 1280 floats
    float* ws_cos = (float*)((char*)d_ws + 8192);        // 1280 floats

    fused_dpp<<<dim3(NBLK), 64, 0, stream>>>(pred, target, ws_sq, ws_cos);
    finalize4<<<1, 256, 0, stream>>>(ws_sq, ws_cos, (float*)d_out);
}

// Round 18
// 31.931 us; speedup vs baseline: 1.1684x; 1.1684x over previous
//
#include <hip/hip_runtime.h>
#include <hip/hip_fp16.h>
#include <math.h>

#define BB 16
#define CC 3
#define HH 512
#define WW 512
#define HW (HH * WW)
#define RAD 5
#define SEGV 16
#define NSEG (HH / SEGV)            // 32 segments per image
#define NSTRIP 3                    // 3 strips: 172,172,168 valid cols (lane-aligned)
#define NTASK (BB * NSEG * NSTRIP)  // 1536 wave-tasks = 1536 single-wave blocks
#define NBLK NTASK                  // 6 blocks/CU exactly
#define NITER (SEGV + 2 * RAD)      // 26 row iterations

// ---- DPP wave-shift helpers (VALU pipe, no DS) ----
#define DPP_WAVE_SHL1 0x130
#define DPP_WAVE_SHR1 0x138

template <int CTRL>
__device__ __forceinline__ float dpp_f(float x) {
    union { float f; int i; } u, o;
    u.f = x;
    o.i = __builtin_amdgcn_update_dpp(0, u.i, CTRL, 0xF, 0xF, true);
    return o.f;
}
template <int CTRL>
__device__ __forceinline__ __half2 dpp_h2(__half2 x) {
    union { __half2 h; int i; } u, o;
    u.h = x;
    o.i = __builtin_amdgcn_update_dpp(0, u.i, CTRL, 0xF, 0xF, true);
    return o.h;
}
#define SHL1F(x) dpp_f<DPP_WAVE_SHL1>(x)
#define SHR1F(x) dpp_f<DPP_WAVE_SHR1>(x)
#define SHL1H(x) dpp_h2<DPP_WAVE_SHL1>(x)
#define SHR1H(x) dpp_h2<DPP_WAVE_SHR1>(x)

// 4 cols/lane (float4 loads). Lane holds col pairs P0=(c0,c1), P1=(c2,c3).
// Horizontal 11-window per output col 4i+k from lane pair-sums:
//   S5_0 = prL(i-1)+prL(i)+pr0(i+1) ; S5_1 = pr1(i-1)+prL(i)+prL(i+1)
//   h(4i)=b1(i-2)+S5_0; h(4i+1)=S5_0+a1(i+1); h(4i+2)=b0(i-1)+S5_1;
//   h(4i+3)=S5_1+a0(i+2)
// Vertical: 11-deep quantized ring + exact-cancellation f32 running sums.
__global__ __launch_bounds__(64) void fused_q4(
    const float* __restrict__ pred, const float* __restrict__ target,
    float* __restrict__ ws_sq, float* __restrict__ ws_cos)
{
    const int lane = threadIdx.x;

    // bijective XCD-contiguous swizzle (1536 % 8 == 0): 192 blocks/XCD
    const int bid = (int)blockIdx.x;
    const int swz = (bid & 7) * (NBLK / 8) + (bid >> 3);

    const int img   = swz / (NSEG * NSTRIP);
    const int rem   = swz % (NSEG * NSTRIP);
    const int seg   = rem / NSTRIP;
    const int strip = rem - seg * NSTRIP;

    const int y0      = seg * SEGV;
    const int colbase = strip * 172 - 8;                 // -8, 164, 336
    const int col0    = colbase + lane * 4;              // 16B aligned
    const int col0c   = min(max(col0, 0), WW - 4);
    // per-lane masks (strip boundaries are lane-aligned by construction)
    const float mx = ((strip == 0 && lane < 2) ||
                      (strip == 2 && lane >= 44)) ? 0.f : 1.f;
    const bool vout = (lane >= 2) && (lane <= (strip == 2 ? 43 : 44));

    const long base = (long)img * (CC * HW);

    // depth-1 prefetch (VGPR-lean)
    float4 P0, P1, P2, T0, T1, T2;
    {
        const int y  = y0 - RAD;
        const int yc = y < 0 ? 0 : y;
        const long off = base + (long)yc * WW + col0c;
        P0 = *(const float4*)(pred + off);
        P1 = *(const float4*)(pred + off + HW);
        P2 = *(const float4*)(pred + off + 2 * HW);
        T0 = *(const float4*)(target + off);
        T1 = *(const float4*)(target + off + HW);
        T2 = *(const float4*)(target + off + 2 * HW);
    }

    // rings: 4 dp-packed outputs + 2 T-packed outputs per row
    __half2 rh0[11], rh1[11], rh2[11], rh3[11], rt01[11], rt23[11];
    float Sd0=0.f,Sd1=0.f,Sd2=0.f,Sd3=0.f;
    float Sp0=0.f,Sp1=0.f,Sp2=0.f,Sp3=0.f;
    float St0=0.f,St1=0.f,St2=0.f,St3=0.f;
    float sq = 0.f, cosacc = 0.f;

    #pragma unroll
    for (int it = 0; it < NITER; ++it) {
        const int y = y0 - RAD + it;
        const float msk = (y >= 0 && y < HH) ? mx : 0.f;

        const float4 p0=P0, p1=P1, p2=P2, t0=T0, t1=T1, t2=T2;
        if (it + 1 < NITER) {                     // prefetch next row
            const int y2  = y0 - RAD + it + 1;
            const int yc2 = min(max(y2, 0), HH - 1);
            const long off2 = base + (long)yc2 * WW + col0c;
            P0 = *(const float4*)(pred + off2);
            P1 = *(const float4*)(pred + off2 + HW);
            P2 = *(const float4*)(pred + off2 + 2 * HW);
            T0 = *(const float4*)(target + off2);
            T1 = *(const float4*)(target + off2 + HW);
            T2 = *(const float4*)(target + off2 + 2 * HW);
        }

        // per-pixel dot/pp/tt for 4 cols, masked
        const float d0=(p0.x*t0.x+p1.x*t1.x+p2.x*t2.x)*msk;
        const float d1=(p0.y*t0.y+p1.y*t1.y+p2.y*t2.y)*msk;
        const float d2=(p0.z*t0.z+p1.z*t1.z+p2.z*t2.z)*msk;
        const float d3=(p0.w*t0.w+p1.w*t1.w+p2.w*t2.w)*msk;
        const float q0=(p0.x*p0.x+p1.x*p1.x+p2.x*p2.x)*msk;
        const float q1=(p0.y*p0.y+p1.y*p1.y+p2.y*p2.y)*msk;
        const float q2=(p0.z*p0.z+p1.z*p1.z+p2.z*p2.z)*msk;
        const float q3=(p0.w*p0.w+p1.w*p1.w+p2.w*p2.w)*msk;
        const float u0=(t0.x*t0.x+t1.x*t1.x+t2.x*t2.x)*msk;
        const float u1=(t0.y*t0.y+t1.y*t1.y+t2.y*t2.y)*msk;
        const float u2=(t0.z*t0.z+t1.z*t1.z+t2.z*t2.z)*msk;
        const float u3=(t0.w*t0.w+t1.w*t1.w+t2.w*t2.w)*msk;

        // PSNR squared error from maps: pp - 2*dot + tt
        if (it >= RAD && it < RAD + SEGV && vout) {
            sq += (q0+u0-2.f*d0)+(q1+u1-2.f*d1)+(q2+u2-2.f*d2)+(q3+u3-2.f*d3);
        }

        // ---- dp-packed horizontal tree ----
        const __half2 A0 = __floats2half2_rn(d0, q0);
        const __half2 B0 = __floats2half2_rn(d1, q1);
        const __half2 A1 = __floats2half2_rn(d2, q2);
        const __half2 B1 = __floats2half2_rn(d3, q3);
        const __half2 pr0 = __hadd2(A0, B0);
        const __half2 pr1 = __hadd2(A1, B1);
        const __half2 prL = __hadd2(pr0, pr1);
        const __half2 s_prL_m1 = SHL1H(prL);
        const __half2 s_prL_p1 = SHR1H(prL);
        const __half2 s_pr0_p1 = SHR1H(pr0);
        const __half2 s_pr1_m1 = SHL1H(pr1);
        const __half2 s_B1_m2  = SHL1H(SHL1H(B1));
        const __half2 s_A1_p1  = SHR1H(A1);
        const __half2 s_B0_m1  = SHL1H(B0);
        const __half2 s_A0_p2  = SHR1H(SHR1H(A0));
        const __half2 S50 = __hadd2(__hadd2(s_prL_m1, prL), s_pr0_p1);
        const __half2 S51 = __hadd2(__hadd2(s_pr1_m1, prL), s_prL_p1);
        const __half2 h0 = __hadd2(s_B1_m2, S50);
        const __half2 h1 = __hadd2(S50, s_A1_p1);
        const __half2 h2 = __hadd2(s_B0_m1, S51);
        const __half2 h3 = __hadd2(S51, s_A0_p2);

        // ---- T tree (f32) ----
        const float prt0 = u0 + u1, prt1 = u2 + u3;
        const float prtL = prt0 + prt1;
        const float tL_m1 = SHL1F(prtL);
        const float tL_p1 = SHR1F(prtL);
        const float t0_p1 = SHR1F(prt0);
        const float t1_m1 = SHL1F(prt1);
        const float tB1m2 = SHL1F(SHL1F(u3));
        const float tA1p1 = SHR1F(u2);
        const float tB0m1 = SHL1F(u1);
        const float tA0p2 = SHR1F(SHR1F(u0));
        const float T50 = (tL_m1 + prtL) + t0_p1;
        const float T51 = (t1_m1 + prtL) + tL_p1;
        const __half2 ht01 = __floats2half2_rn(tB1m2 + T50, T50 + tA1p1);
        const __half2 ht23 = __floats2half2_rn(tB0m1 + T51, T51 + tA0p2);

        // accumulate QUANTIZED values -> ring subtract cancels exactly
        const float2 f0 = __half22float2(h0);
        const float2 f1 = __half22float2(h1);
        const float2 f2 = __half22float2(h2);
        const float2 f3 = __half22float2(h3);
        const float2 g01 = __half22float2(ht01);
        const float2 g23 = __half22float2(ht23);
        Sd0 += f0.x; Sp0 += f0.y;
        Sd1 += f1.x; Sp1 += f1.y;
        Sd2 += f2.x; Sp2 += f2.y;
        Sd3 += f3.x; Sp3 += f3.y;
        St0 += g01.x; St1 += g01.y;
        St2 += g23.x; St3 += g23.y;

        if (it >= 10) {
            if (vout) {
                cosacc += Sd0 * rsqrtf(fmaxf(Sp0 * St0, 1e-20f));
                cosacc += Sd1 * rsqrtf(fmaxf(Sp1 * St1, 1e-20f));
                cosacc += Sd2 * rsqrtf(fmaxf(Sp2 * St2, 1e-20f));
                cosacc += Sd3 * rsqrtf(fmaxf(Sp3 * St3, 1e-20f));
            }
            const float2 o0 = __half22float2(rh0[(it + 1) % 11]);
            const float2 o1 = __half22float2(rh1[(it + 1) % 11]);
            const float2 o2 = __half22float2(rh2[(it + 1) % 11]);
            const float2 o3 = __half22float2(rh3[(it + 1) % 11]);
            const float2 w01 = __half22float2(rt01[(it + 1) % 11]);
            const float2 w23 = __half22float2(rt23[(it + 1) % 11]);
            Sd0 -= o0.x; Sp0 -= o0.y;
            Sd1 -= o1.x; Sp1 -= o1.y;
            Sd2 -= o2.x; Sp2 -= o2.y;
            Sd3 -= o3.x; Sp3 -= o3.y;
            St0 -= w01.x; St1 -= w01.y;
            St2 -= w23.x; St3 -= w23.y;
        }
        rh0[it % 11] = h0;
        rh1[it % 11] = h1;
        rh2[it % 11] = h2;
        rh3[it % 11] = h3;
        rt01[it % 11] = ht01;
        rt23[it % 11] = ht23;
    }

    // wave reduce -> per-block (= per-wave) partial stores
    #pragma unroll
    for (int o = 32; o > 0; o >>= 1) {
        cosacc += __shfl_down(cosacc, o);
        sq     += __shfl_down(sq, o);
    }
    if (lane == 0) {
        ws_cos[swz] = cosacc;
        ws_sq [swz] = sq;
    }
}

// ---------------- finalize: 1536 sq + 1536 cos partials ----------------
__global__ __launch_bounds__(256) void finalize6(
    const float* __restrict__ ws_sq, const float* __restrict__ ws_cos,
    float* __restrict__ out)
{
    __shared__ float sq_b[16];
    __shared__ float cred[4];
    const int tid = threadIdx.x;

    // sq: 96 partials per image; 16 threads/image, 6 values each
    const int b = tid >> 4, j = tid & 15;
    float s = 0.f;
    #pragma unroll
    for (int k = 0; k < 6; ++k) s += ws_sq[b * 96 + j * 6 + k];
    #pragma unroll
    for (int o = 8; o > 0; o >>= 1) s += __shfl_down(s, o, 16);
    if (j == 0) sq_b[b] = s;

    float c = 0.f;
    #pragma unroll
    for (int k = 0; k < 6; ++k) c += ws_cos[tid + 256 * k];
    #pragma unroll
    for (int o = 32; o > 0; o >>= 1) c += __shfl_down(c, o);
    if ((tid & 63) == 0) cred[tid >> 6] = c;
    __syncthreads();

    if (tid == 0) {
        const float csum = cred[0] + cred[1] + cred[2] + cred[3];
        const float scale = 4.342944819032518f;   // 10 / ln(10)
        float lsum = 0.f;
        for (int bb = 0; bb < 16; ++bb)
            lsum += logf(sq_b[bb] / (float)(CC * HW) + 1e-8f);
        out[0] = scale * (lsum / (float)BB) + (1.f - csum / (float)(BB * HW));
    }
}

extern "C" void kernel_launch(void* const* d_in, const int* in_sizes, int n_in,
                              void* d_out, int out_size, void* d_ws, size_t ws_size,
                              hipStream_t stream)
{
    const float* pred   = (const float*)d_in[0];
    const float* target = (const float*)d_in[1];

    float* ws_sq  = (float*)d_ws;                        // 1536 floats
    float* ws_cos = (float*)((char*)d_ws + 8192);        // 1536 floats

    fused_q4<<<dim3(NBLK), 64, 0, stream>>>(pred, target, ws_sq, ws_cos);
    finalize6<<<1, 256, 0, stream>>>(ws_sq, ws_cos, (float*)d_out);
}